// Round 1
// 1249.840 us; speedup vs baseline: 1.1367x; 1.1367x over previous
//
#include <hip/hip_runtime.h>
#include <hip/hip_bf16.h>

// GraphConvolution on MI355X:
//   supT = (input @ W^T + b)^T  computed as  W @ input^T + b[row]  (NT GEMM, bf16 MFMA)
//   out_u = deg_u * (adj  @ sup_i)  = NT GEMM(A=adj_bf,  B=supT+8192 rows)
//   out_i = deg_i * (adjT @ sup_u)  = NT GEMM(A=adjT_bf, B=supT)
// GEMM: 256x256 tile, BK=64, 8 waves (2Mx4N), double-buffered LDS (128 KiB),
// phased schedule with counted vmcnt (T3+T4) + setprio (T5) per guide §5/§5.5.
// Workspace layout (>= 320 MiB):
//   [0,64Mi)    supT   2048x16384 bf16
//   [64,128Mi)  in_bf  16384x2048 bf16   -- reused by adj_bf after GEMM1
//   [128,136Mi) W_bf   2048x2048  bf16   -- dead after GEMM1
//   [64,192Mi)  adj_bf 8192x8192  bf16
//   [192,320Mi) adjT   8192x8192  bf16

typedef __bf16 bf16;
typedef bf16 bf16x4 __attribute__((ext_vector_type(4)));
typedef bf16 bf16x8 __attribute__((ext_vector_type(8)));
typedef float f32x4 __attribute__((ext_vector_type(4)));

#define AS1 __attribute__((address_space(1)))
#define AS3 __attribute__((address_space(3)))

// ---------------- fp32 -> bf16 straight convert (4 elems/thread) ----------------
__global__ __launch_bounds__(256) void k_cvt(const float* __restrict__ src,
                                             bf16* __restrict__ dst) {
  long i = ((long)blockIdx.x * 256 + threadIdx.x) * 4;
  float4 v = *(const float4*)(src + i);
  bf16x4 o;
  o.x = (bf16)v.x; o.y = (bf16)v.y; o.z = (bf16)v.z; o.w = (bf16)v.w;
  *(bf16x4*)(dst + i) = o;
}

// ---------------- adj: fused straight-cvt + transpose-cvt (reads adj ONCE) ------
__global__ __launch_bounds__(256) void k_adj_cvt(const float* __restrict__ src,
                                                 bf16* __restrict__ dst,
                                                 bf16* __restrict__ dstT, int n) {
  __shared__ float tile[64][65];
  const int bx = blockIdx.x * 64;  // source col block
  const int by = blockIdx.y * 64;  // source row block
  const int tx = threadIdx.x & 15, ty = threadIdx.x >> 4;
#pragma unroll
  for (int p = 0; p < 4; ++p) {
    const long r = by + p * 16 + ty;
    float4 v = *(const float4*)(src + r * n + bx + tx * 4);
    tile[p * 16 + ty][tx * 4 + 0] = v.x;
    tile[p * 16 + ty][tx * 4 + 1] = v.y;
    tile[p * 16 + ty][tx * 4 + 2] = v.z;
    tile[p * 16 + ty][tx * 4 + 3] = v.w;
    bf16x4 o;
    o.x = (bf16)v.x; o.y = (bf16)v.y; o.z = (bf16)v.z; o.w = (bf16)v.w;
    *(bf16x4*)(dst + r * n + bx + tx * 4) = o;
  }
  __syncthreads();
#pragma unroll
  for (int p = 0; p < 4; ++p) {
    bf16x4 o;
    o.x = (bf16)tile[tx * 4 + 0][p * 16 + ty];
    o.y = (bf16)tile[tx * 4 + 1][p * 16 + ty];
    o.z = (bf16)tile[tx * 4 + 2][p * 16 + ty];
    o.w = (bf16)tile[tx * 4 + 3][p * 16 + ty];
    *(bf16x4*)(dstT + (long)(bx + p * 16 + ty) * n + by + tx * 4) = o;
  }
}

// ---------------- staging helpers (global -> LDS, width 16, swizzled source) ----
// A storage: LDS row = tile row (0..255), 8x16B chunks per row, chunk slot s holds
// global k-chunk (s ^ (row&7)).  Granule g: rows [g*64,(g+1)*64) of each 128-half
// (i.e. rows {0-63,128-191} for g=0) -- exactly what MFMA phases mh=g consume.
__device__ __forceinline__ void stage_a(const bf16* Ab, bf16* lds, int lda, int k0,
                                        int g, int tid) {
#pragma unroll
  for (int it = 0; it < 2; ++it) {
    const int u = it * 512 + tid;                                   // 0..1023
    const int row = ((u >> 9) << 7) + (g << 6) + ((u >> 3) & 63);   // tile row
    const int kc = (((u & 7) ^ (row & 7)) << 3);                    // swizzled k
    const int c = ((u >> 9) << 10) + (g << 9) + (u & 511);          // lds chunk
    __builtin_amdgcn_global_load_lds((const AS1 void*)(Ab + (long)row * lda + k0 + kc),
                                     (AS3 void*)(lds + c * 8), 16, 0, 0);
  }
}

// B storage is PERMUTED: storage row r = nh*128 + wn*32 + w  <->  physical row
// p = wn*64 + nh*32 + w, so granule g=nh occupies a contiguous 128-row half.
__device__ __forceinline__ void stage_b(const bf16* Bb, bf16* lds, int ldb, int k0,
                                        int g, int tid) {
#pragma unroll
  for (int it = 0; it < 2; ++it) {
    const int u = it * 512 + tid;                                   // 0..1023
    const int r = (g << 7) + (u >> 3);                              // storage row
    const int p = (((u >> 8) & 3) << 6) + (g << 5) + ((u >> 3) & 31);  // phys row
    const int kc = (((u & 7) ^ (r & 7)) << 3);
    __builtin_amdgcn_global_load_lds((const AS1 void*)(Bb + (long)p * ldb + k0 + kc),
                                     (AS3 void*)(lds + ((g << 10) + u) * 8), 16, 0, 0);
  }
}

template <int MH, int NH>
__device__ __forceinline__ void mfma_phase(f32x4 (&acc)[8][4],
                                           const bf16x8 (&af)[4][2],
                                           const bf16x8 (&bfr)[2][2][2]) {
  __builtin_amdgcn_s_setprio(1);
#pragma unroll
  for (int i = 0; i < 4; ++i)
#pragma unroll
    for (int j = 0; j < 2; ++j)
#pragma unroll
      for (int ks = 0; ks < 2; ++ks)
        acc[MH * 4 + i][NH * 2 + j] = __builtin_amdgcn_mfma_f32_16x16x32_bf16(
            af[i][ks], bfr[NH][j][ks], acc[MH * 4 + i][NH * 2 + j], 0, 0, 0);
  __builtin_amdgcn_s_setprio(0);
}

// ---------------- NT bf16 GEMM, 256x256 phased schedule ----------------
// C[m][n] = rowscale[m] * (sum_k A[m][k]*B[n][k]) + rowbias[m]
// 512 threads = 8 waves (wm=wave>>2 in {0,1}, wn=wave&3). Wave tile 128x64.
// Per K-tile: 4 phases (mh,nh) x 16 MFMA. Staging for tile t+1 issued in
// P0/P1 of tile t; each granule covered by per-wave vmcnt(4) BEFORE a
// collective barrier preceding its consumers (race-free counted-vmcnt).
template <bool OUT_BF16>
__global__ __launch_bounds__(512, 2) void k_gemm_nt_8p(
    const bf16* __restrict__ A, const bf16* __restrict__ B, void* __restrict__ Cout,
    int K, int lda, int ldb, int ldc,
    const float* __restrict__ rowscale, const float* __restrict__ rowbias) {
  __shared__ __align__(16) bf16 As[2][256 * 64];
  __shared__ __align__(16) bf16 Bs[2][256 * 64];
  const int tid = threadIdx.x;
  const int wave = tid >> 6, lane = tid & 63;
  const int quad = lane >> 4, l16 = lane & 15;
  const int wm = wave >> 2, wn = wave & 3;
  const int xm = l16 & 7;
  const int bm = blockIdx.y * 256, bn = blockIdx.x * 256;
  const bf16* Ab = A + (long)bm * lda;
  const bf16* Bb = B + (long)bn * ldb;

  f32x4 acc[8][4] = {};
  bf16x8 af[4][2], bfr[2][2][2];

  // Prologue: stage tile 0 (order: Aq0, Bev, Aq1, Bod), wait the first two.
  stage_a(Ab, As[0], lda, 0, 0, tid);
  stage_b(Bb, Bs[0], ldb, 0, 0, tid);
  stage_a(Ab, As[0], lda, 0, 1, tid);
  stage_b(Bb, Bs[0], ldb, 0, 1, tid);
  asm volatile("s_waitcnt vmcnt(4)" ::: "memory");
  __builtin_amdgcn_s_barrier();

  const int nt = K >> 6;
  for (int t = 0; t < nt; ++t) {
    const int cur = t & 1, nx = cur ^ 1;
    const int k1 = (t + 1) << 6;
    const bool pre = (t + 1) < nt;
    const bf16* Ac = As[cur];
    const bf16* Bc = Bs[cur];

    // ---- P0: mh=0, nh=0 (reads af0 + bf0; stages Aq0/Bev of tile t+1) ----
#pragma unroll
    for (int i = 0; i < 4; ++i)
#pragma unroll
      for (int ks = 0; ks < 2; ++ks)
        af[i][ks] = *(const bf16x8*)(Ac + (wm * 128 + i * 16 + l16) * 64 +
                                     ((((ks << 2) + quad) ^ xm) << 3));
#pragma unroll
    for (int j = 0; j < 2; ++j)
#pragma unroll
      for (int ks = 0; ks < 2; ++ks)
        bfr[0][j][ks] = *(const bf16x8*)(Bc + (wn * 32 + j * 16 + l16) * 64 +
                                         ((((ks << 2) + quad) ^ xm) << 3));
    if (pre) {
      stage_a(Ab, As[nx], lda, k1, 0, tid);
      stage_b(Bb, Bs[nx], ldb, k1, 0, tid);
    }
    __builtin_amdgcn_s_barrier();
    asm volatile("s_waitcnt lgkmcnt(0)" ::: "memory");
    __builtin_amdgcn_sched_barrier(0);
    mfma_phase<0, 0>(acc, af, bfr);
    // Cover Bod(t)/Aq1(t) (issued at t-1.P1) before P1/P2 read them.
    if (pre) asm volatile("s_waitcnt vmcnt(4)" ::: "memory");
    else     asm volatile("s_waitcnt vmcnt(0)" ::: "memory");
    __builtin_amdgcn_s_barrier();

    // ---- P1: mh=0, nh=1 (reads bf1; stages Aq1/Bod of tile t+1) ----
#pragma unroll
    for (int j = 0; j < 2; ++j)
#pragma unroll
      for (int ks = 0; ks < 2; ++ks)
        bfr[1][j][ks] = *(const bf16x8*)(Bc + (128 + wn * 32 + j * 16 + l16) * 64 +
                                         ((((ks << 2) + quad) ^ xm) << 3));
    if (pre) {
      stage_a(Ab, As[nx], lda, k1, 1, tid);
      stage_b(Bb, Bs[nx], ldb, k1, 1, tid);
    }
    __builtin_amdgcn_s_barrier();
    asm volatile("s_waitcnt lgkmcnt(0)" ::: "memory");
    __builtin_amdgcn_sched_barrier(0);
    mfma_phase<0, 1>(acc, af, bfr);
    __builtin_amdgcn_s_barrier();

    // ---- P2: mh=1, nh=0 (reads af1) ----
#pragma unroll
    for (int i = 0; i < 4; ++i)
#pragma unroll
      for (int ks = 0; ks < 2; ++ks)
        af[i][ks] = *(const bf16x8*)(Ac + (wm * 128 + 64 + i * 16 + l16) * 64 +
                                     ((((ks << 2) + quad) ^ xm) << 3));
    __builtin_amdgcn_s_barrier();
    asm volatile("s_waitcnt lgkmcnt(0)" ::: "memory");
    __builtin_amdgcn_sched_barrier(0);
    mfma_phase<1, 0>(acc, af, bfr);
    __builtin_amdgcn_s_barrier();

    // ---- P3: mh=1, nh=1 (no reads) + tile boundary ----
    mfma_phase<1, 1>(acc, af, bfr);
    if (pre) {
      // Cover Aq0(t+1)/Bev(t+1) (issued this tile's P0) before next P0 reads.
      asm volatile("s_waitcnt vmcnt(4)" ::: "memory");
      __builtin_amdgcn_s_barrier();
    }
  }

  // Epilogue: C/D layout col=lane&15, row=quad*4+reg (guide §3, m89-verified).
#pragma unroll
  for (int mi = 0; mi < 8; ++mi) {
    const int r0 = bm + wm * 128 + mi * 16 + quad * 4;
    float sc[4], bi[4];
#pragma unroll
    for (int r = 0; r < 4; ++r) {
      sc[r] = rowscale ? rowscale[r0 + r] : 1.0f;
      bi[r] = rowbias ? rowbias[r0 + r] : 0.0f;
    }
#pragma unroll
    for (int j = 0; j < 4; ++j) {
      const int col = bn + wn * 64 + j * 16 + l16;
#pragma unroll
      for (int r = 0; r < 4; ++r) {
        float v = acc[mi][j][r] * sc[r] + bi[r];
        long idx = (long)(r0 + r) * ldc + col;
        if (OUT_BF16) ((bf16*)Cout)[idx] = (bf16)v;
        else          ((float*)Cout)[idx] = v;
      }
    }
  }
}

extern "C" void kernel_launch(void* const* d_in, const int* in_sizes, int n_in,
                              void* d_out, int out_size, void* d_ws, size_t ws_size,
                              hipStream_t stream) {
  const float* input  = (const float*)d_in[0];  // (16384, 2048)
  const float* adj    = (const float*)d_in[1];  // (8192, 8192)
  const float* degree = (const float*)d_in[2];  // (16384,)
  const float* W      = (const float*)d_in[3];  // (2048, 2048)
  const float* b      = (const float*)d_in[4];  // (2048,)
  float* out = (float*)d_out;                   // (16384, 2048) fp32

  char* ws = (char*)d_ws;
  bf16* supT   = (bf16*)(ws);                    // 2048 x 16384
  bf16* in_bf  = (bf16*)(ws + (64ULL  << 20));   // 16384 x 2048
  bf16* W_bf   = (bf16*)(ws + (128ULL << 20));   // 2048 x 2048
  bf16* adj_bf = (bf16*)(ws + (64ULL  << 20));   // 8192 x 8192 (reuses in_bf region)
  bf16* adjT   = (bf16*)(ws + (192ULL << 20));   // 8192 x 8192

  // Phase 0: convert GEMM1 operands.
  k_cvt<<<(16384 * 2048 / 4) / 256, 256, 0, stream>>>(input, in_bf);
  k_cvt<<<(2048 * 2048 / 4) / 256, 256, 0, stream>>>(W, W_bf);

  // Phase 1: supT = W @ input^T + b[row].  M=2048, N=16384, K=2048.
  k_gemm_nt_8p<true><<<dim3(16384 / 256, 2048 / 256), 512, 0, stream>>>(
      W_bf, in_bf, supT, 2048, 2048, 2048, 16384, nullptr, b);

  // Phase 2: adj conversions, fused single pass over adj
  // (adj_bf overwrites in_bf -- GEMM1 already done).
  k_adj_cvt<<<dim3(128, 128), 256, 0, stream>>>(adj, adj_bf, adjT, 8192);

  // Phase 3: out_u = deg_u * (adj @ sup_i).  M=8192, N=2048, K=8192.
  k_gemm_nt_8p<false><<<dim3(2048 / 256, 8192 / 256), 512, 0, stream>>>(
      adj_bf, supT + 8192, out, 8192, 8192, 16384, 2048, degree, nullptr);

  // Phase 4: out_i = deg_i * (adjT @ sup_u).
  k_gemm_nt_8p<false><<<dim3(2048 / 256, 8192 / 256), 512, 0, stream>>>(
      adjT, supT, out + 8192LL * 2048, 8192, 8192, 16384, 2048, degree + 8192, nullptr);
}